// Round 2
// baseline (218.892 us; speedup 1.0000x reference)
//
#include <hip/hip_runtime.h>
#include <math.h>

#define SZ 256
#define KNN 4
#define NUM_CHANNELS 8

// Exact top-4: keys ascending, key = (d2_int << 16) | flat_idx.
// Matches jax.lax.top_k semantics (smallest d2 first, ties -> lower index).
__device__ __forceinline__ void insert_key(unsigned long long key,
                                           unsigned long long& k0,
                                           unsigned long long& k1,
                                           unsigned long long& k2,
                                           unsigned long long& k3) {
    if (key < k3) {
        if (key < k2) {
            k3 = k2;
            if (key < k1) {
                k2 = k1;
                if (key < k0) { k1 = k0; k0 = key; }
                else          { k1 = key; }
            } else {
                k2 = key;
            }
        } else {
            k3 = key;
        }
    }
}

// Pass 1: per-channel occupancy bitmaps via wave ballot.
// bm layout: u64[NUM_CHANNELS][SZ][4]; word j covers x in [j*64, j*64+64).
__global__ __launch_bounds__(256) void build_bitmaps(
    const int* __restrict__ lut,
    unsigned long long* __restrict__ bm)
{
    const int y = blockIdx.x;           // one block per row
    const int x = threadIdx.x;
    const int v = lut[y * SZ + x];
    const int lane = threadIdx.x & 63;
    const int w64 = x >> 6;             // wave id == word index (4 waves/block)
    #pragma unroll
    for (int c = 1; c <= NUM_CHANNELS; ++c) {
        unsigned long long bal = __ballot(v == c);
        if (lane == 0) bm[(size_t)(c - 1) * (SZ * 4) + y * 4 + w64] = bal;
    }
}

// Pass 2: exact KNN fill using LDS-resident channel bitmap.
__global__ __launch_bounds__(256) void knn_fill(
    const float* __restrict__ img,
    const unsigned long long* __restrict__ bm,
    float* __restrict__ out)
{
    __shared__ unsigned long long rows[SZ * 4];   // 8 KB: whole channel bitmap

    const int x = threadIdx.x;
    const int y = blockIdx.x;
    const int ch = blockIdx.y;

    const unsigned long long* bmc = bm + (size_t)ch * (SZ * 4);
    for (int i = threadIdx.x; i < SZ * 4; i += 256) rows[i] = bmc[i];
    __syncthreads();

    const int pix = y * SZ + x;
    float* outc = out + (size_t)ch * (SZ * SZ);

    // Filled pixel: pass through.
    if ((rows[y * 4 + (x >> 6)] >> (x & 63)) & 1ull) {
        outc[pix] = img[pix];
        return;
    }

    unsigned long long k0 = ~0ull, k1 = ~0ull, k2 = ~0ull, k3 = ~0ull;

    for (int ady = 0; ady < SZ; ++ady) {
        const unsigned long long cur = k3 >> 16;              // current 4th-best d2
        const unsigned long long a2 = (unsigned long long)(ady * ady);
        if (a2 > cur) break;   // strict: equal-d2 ties in this row still examined

        // Admissible |dx|: dx^2 <= cur - a2. Conservative +1 keeps exactness.
        int R;
        const unsigned long long bound = cur - a2;
        if (bound >= 65025ull) R = SZ - 1;
        else R = (int)sqrtf((float)bound) + 1;

        int xs = x - R; if (xs < 0) xs = 0;
        int xe = x + R; if (xe > SZ - 1) xe = SZ - 1;
        const int jxs = xs >> 6, jxe = xe >> 6;
        const unsigned long long mlo = (~0ull) << (xs & 63);
        const unsigned long long mhi = (~0ull) >> (63 - (xe & 63));

        #pragma unroll
        for (int s = 0; s < 2; ++s) {
            if (s && ady == 0) continue;
            const int yy = s ? y + ady : y - ady;
            if (yy < 0 || yy > SZ - 1) continue;
            const unsigned long long* rw = &rows[yy * 4];
            const int rowbase = yy * SZ;
            for (int j = jxs; j <= jxe; ++j) {
                unsigned long long w = rw[j];
                if (j == jxs) w &= mlo;
                if (j == jxe) w &= mhi;
                while (w) {
                    const int b = __builtin_ctzll(w);
                    w &= w - 1;
                    const int xx = (j << 6) + b;
                    const int dx = xx - x;
                    const unsigned long long d2 =
                        a2 + (unsigned long long)(dx * dx);
                    const unsigned long long key =
                        (d2 << 16) | (unsigned)(rowbase + xx);
                    insert_key(key, k0, k1, k2, k3);
                }
            }
        }
    }

    // Weighted sum in top_k order (ascending (d2, idx)), matching reference.
    unsigned long long ks[KNN] = { k0, k1, k2, k3 };
    float num = 0.0f, den = 0.0f;
    #pragma unroll
    for (int i = 0; i < KNN; ++i) {
        const int idx = (int)(ks[i] & 0xFFFFull);
        const int d2i = (int)(ks[i] >> 16);
        const float dist = sqrtf((float)d2i * (1.0f / 65536.0f));
        num += img[idx] * dist;
        den += dist;
    }
    outc[pix] = num / den;
}

extern "C" void kernel_launch(void* const* d_in, const int* in_sizes, int n_in,
                              void* d_out, int out_size, void* d_ws, size_t ws_size,
                              hipStream_t stream) {
    const float* img = (const float*)d_in[0];   // coded: [1,1,256,256] f32
    const int*   lut = (const int*)d_in[1];     // lookup_table: [256,256] i32
    float*       out = (float*)d_out;           // [1,8,256,256] f32
    unsigned long long* bm = (unsigned long long*)d_ws;  // 64 KB bitmaps

    build_bitmaps<<<dim3(SZ), dim3(256), 0, stream>>>(lut, bm);
    knn_fill<<<dim3(SZ, NUM_CHANNELS), dim3(256), 0, stream>>>(img, bm, out);
}

// Round 3
// 86.520 us; speedup vs baseline: 2.5300x; 2.5300x over previous
//
#include <hip/hip_runtime.h>
#include <math.h>

#define SZ 256
#define KNN 4
#define NUM_CHANNELS 8
#define R 7                  // phase-1 Chebyshev radius (window 15x15)
#define WROWS (2 * R + 1)    // 15
#define RSTRIDE 6            // LDS row: [zero pad][4 row words][zero pad]

typedef unsigned long long u64;

// Branchless insert into ascending sorted 4 (k0<=k1<=k2<=k3).
// key = (d2_int << 16) | flat_idx — matches jax.lax.top_k ordering incl. ties.
__device__ __forceinline__ void insert_key(u64 key, u64& k0, u64& k1,
                                           u64& k2, u64& k3) {
    if (key < k3) {           // single divergence level; body is straight-line
        u64 mx;
        mx = (k2 > key) ? k2 : key;  k3 = (k3 < mx) ? k3 : mx;   // uses old k2
        mx = (k1 > key) ? k1 : key;  k2 = (k2 < mx) ? k2 : mx;   // uses old k1
        mx = (k0 > key) ? k0 : key;  k1 = (k1 < mx) ? k1 : mx;   // uses old k0
        k0 = (k0 < key) ? k0 : key;
    }
}

// Pass 1: per-channel occupancy bitmaps via wave ballot.
// bm layout: u64[NUM_CHANNELS][SZ][4]; word j covers x in [j*64, j*64+64).
__global__ __launch_bounds__(256) void build_bitmaps(
    const int* __restrict__ lut,
    u64* __restrict__ bm)
{
    const int y = blockIdx.x;
    const int x = threadIdx.x;
    const int v = lut[y * SZ + x];
    const int lane = threadIdx.x & 63;
    const int w64 = x >> 6;
    #pragma unroll
    for (int c = 1; c <= NUM_CHANNELS; ++c) {
        u64 bal = __ballot(v == c);
        if (lane == 0) bm[(size_t)(c - 1) * (SZ * 4) + y * 4 + w64] = bal;
    }
}

// Pass 2: uniform fixed-window KNN; rare exact adaptive fallback.
__global__ __launch_bounds__(256) void knn_fill(
    const float* __restrict__ img,
    const u64* __restrict__ bm,
    float* __restrict__ out)
{
    __shared__ u64 win[WROWS * RSTRIDE];   // 720 B

    const int x = threadIdx.x;
    const int y = blockIdx.x;              // block-uniform -> uniform row loop
    const int ch = blockIdx.y;
    const u64* bmc = bm + (size_t)ch * (SZ * 4);

    // Stage rows y-R..y+R, zero-padded horizontally and for OOB rows.
    for (int i = threadIdx.x; i < WROWS * RSTRIDE; i += 256) {
        const int rr = i / RSTRIDE, j = i - rr * RSTRIDE;
        const int yy = y - R + rr;
        u64 v = 0;
        if (j >= 1 && j <= 4 && yy >= 0 && yy < SZ) v = bmc[yy * 4 + (j - 1)];
        win[i] = v;
    }
    __syncthreads();

    const int pix = y * SZ + x;
    float* outc = out + (size_t)ch * (SZ * SZ);

    const bool is_filled =
        (win[R * RSTRIDE + 1 + (x >> 6)] >> (x & 63)) & 1ull;
    if (is_filled) {
        outc[pix] = img[pix];
        return;
    }

    u64 k0 = ~0ull, k1 = ~0ull, k2 = ~0ull, k3 = ~0ull;

    const int base = x - R + 64;   // bit offset into padded row
    const int wrd = base >> 6;      // 0..4
    const int sh  = base & 63;

    #pragma unroll
    for (int rr = 0; rr < WROWS; ++rr) {
        const u64 lo = win[rr * RSTRIDE + wrd];
        const u64 hi = win[rr * RSTRIDE + wrd + 1];
        u64 w = (u64)(((((unsigned __int128)hi) << 64) | lo) >> sh)
                & ((1u << WROWS) - 1);
        const int dy = rr - R;
        const int dy2 = dy * dy;
        const int rowbase = (y + dy) * SZ;   // w==0 for OOB rows, never used
        while (w) {
            const int b = __builtin_ctzll(w);
            w &= w - 1;
            const int dx = b - R;
            const u64 d2 = (u64)(dy2 + dx * dx);
            const u64 key = (d2 << 16) | (unsigned)(rowbase + x + dx);
            insert_key(key, k0, k1, k2, k3);
        }
    }

    // Exactness check: outside the window d2 >= (R+1)^2 = 64. If our 4th-best
    // d2 < 64 strictly, no outside candidate can beat or tie it.
    if ((k3 >> 16) >= (u64)((R + 1) * (R + 1))) {
        // Rare exact fallback: adaptive ring scan over the global bitmap.
        k0 = k1 = k2 = k3 = ~0ull;
        for (int ady = 0; ady < SZ; ++ady) {
            const u64 cur = k3 >> 16;
            const u64 a2 = (u64)(ady * ady);
            if (a2 > cur) break;
            int Rx;
            const u64 bound = cur - a2;
            if (bound >= 65025ull) Rx = SZ - 1;
            else Rx = (int)sqrtf((float)bound) + 1;
            int xs = x - Rx; if (xs < 0) xs = 0;
            int xe = x + Rx; if (xe > SZ - 1) xe = SZ - 1;
            const int jxs = xs >> 6, jxe = xe >> 6;
            const u64 mlo = (~0ull) << (xs & 63);
            const u64 mhi = (~0ull) >> (63 - (xe & 63));
            for (int s = 0; s < 2; ++s) {
                if (s && ady == 0) continue;
                const int yy = s ? y + ady : y - ady;
                if (yy < 0 || yy > SZ - 1) continue;
                const int rb = yy * SZ;
                for (int j = jxs; j <= jxe; ++j) {
                    u64 w = bmc[yy * 4 + j];
                    if (j == jxs) w &= mlo;
                    if (j == jxe) w &= mhi;
                    while (w) {
                        const int b = __builtin_ctzll(w);
                        w &= w - 1;
                        const int xx = (j << 6) + b;
                        const int dxx = xx - x;
                        const u64 d2 = a2 + (u64)(dxx * dxx);
                        insert_key((d2 << 16) | (unsigned)(rb + xx),
                                   k0, k1, k2, k3);
                    }
                }
            }
        }
    }

    // Weighted sum in top_k order (ascending (d2, idx)), matching reference.
    u64 ks[KNN] = { k0, k1, k2, k3 };
    float num = 0.0f, den = 0.0f;
    #pragma unroll
    for (int i = 0; i < KNN; ++i) {
        const int idx = (int)(ks[i] & 0xFFFFull);
        const int d2i = (int)(ks[i] >> 16);
        const float dist = sqrtf((float)d2i * (1.0f / 65536.0f));
        num += img[idx] * dist;
        den += dist;
    }
    outc[pix] = num / den;
}

extern "C" void kernel_launch(void* const* d_in, const int* in_sizes, int n_in,
                              void* d_out, int out_size, void* d_ws, size_t ws_size,
                              hipStream_t stream) {
    const float* img = (const float*)d_in[0];   // coded: [1,1,256,256] f32
    const int*   lut = (const int*)d_in[1];     // lookup_table: [256,256] i32
    float*       out = (float*)d_out;           // [1,8,256,256] f32
    u64*         bm  = (u64*)d_ws;              // 64 KB bitmaps

    build_bitmaps<<<dim3(SZ), dim3(256), 0, stream>>>(lut, bm);
    knn_fill<<<dim3(SZ, NUM_CHANNELS), dim3(256), 0, stream>>>(img, bm, out);
}